// Round 1
// baseline (184.351 us; speedup 1.0000x reference)
//
#include <hip/hip_runtime.h>
#include <cstddef>

// DynamicRouting: B=32, C1=4096, C2=32, D2=16, 3 routing iterations.
// digit_caps_stopped == digit_caps (values identical) -> read d_in[0] only.
//
// iter0: w = 1/32 uniform  -> v0 = squash(colsum(x)/32 + bias)
// iter1: a0 = x.v0, w1 = softmax_c2(a0)      -> v1 = squash(sum_c1 w1*x + bias)
// iter2: a  = a0 + x.v1, w2 = softmax_c2(a)  -> out = squash(sum_c1 w2*x + bias)
// (a0 recomputed in pass 2 -- cheaper than 32 MB of HBM round-trip.)

namespace {
constexpr int B_  = 32;
constexpr int C1_ = 4096;
constexpr int C2_ = 32;
constexpr int D2_ = 16;
constexpr int ROW_ = C2_ * D2_;                 // 512 floats per (b,c1)
constexpr int BLOCKS_PER_B = 32;
constexpr int C1_PER_BLK = C1_ / BLOCKS_PER_B;  // 128

template <int PHASE>
__global__ __launch_bounds__(256) void routing_pass(
    const float* __restrict__ x, const float* __restrict__ v0,
    const float* __restrict__ v1, float* __restrict__ P /*[B][BPB][512]*/) {
  const int tid = threadIdx.x;
  const int c2  = tid & 31;   // lane's capsule2 index
  const int rs  = tid >> 5;   // row slot 0..7
  const int b   = blockIdx.x / BLOCKS_PER_B;
  const int blk = blockIdx.x % BLOCKS_PER_B;

  float4 va[4], vb[4];
  if (PHASE >= 1) {
    const float4* vp = reinterpret_cast<const float4*>(v0 + (size_t)b * ROW_ + c2 * D2_);
#pragma unroll
    for (int j = 0; j < 4; ++j) va[j] = vp[j];
  }
  if (PHASE == 2) {
    const float4* vp = reinterpret_cast<const float4*>(v1 + (size_t)b * ROW_ + c2 * D2_);
#pragma unroll
    for (int j = 0; j < 4; ++j) vb[j] = vp[j];
  }

  float4 acc[4];
#pragma unroll
  for (int j = 0; j < 4; ++j) acc[j] = make_float4(0.f, 0.f, 0.f, 0.f);

  const size_t base =
      ((size_t)b * C1_ + (size_t)blk * C1_PER_BLK) * ROW_ + (size_t)c2 * D2_;
  for (int r = rs; r < C1_PER_BLK; r += 8) {
    const float4* xp = reinterpret_cast<const float4*>(x + base + (size_t)r * ROW_);
    float4 xr[4];
#pragma unroll
    for (int j = 0; j < 4; ++j) xr[j] = xp[j];

    float w = 1.0f;  // PHASE 0: uniform weights (1/32 folded into squash scale)
    if (PHASE >= 1) {
      float a = 0.f;
#pragma unroll
      for (int j = 0; j < 4; ++j)
        a += xr[j].x * va[j].x + xr[j].y * va[j].y + xr[j].z * va[j].z + xr[j].w * va[j].w;
      if (PHASE == 2) {
#pragma unroll
        for (int j = 0; j < 4; ++j)
          a += xr[j].x * vb[j].x + xr[j].y * vb[j].y + xr[j].z * vb[j].z + xr[j].w * vb[j].w;
      }
      // softmax over the 32-lane c2 group (lanes [0..31] / [32..63] independent)
      float m = a;
#pragma unroll
      for (int off = 16; off; off >>= 1) m = fmaxf(m, __shfl_xor(m, off, 32));
      float e = __expf(a - m);
      float s = e;
#pragma unroll
      for (int off = 16; off; off >>= 1) s += __shfl_xor(s, off, 32);
      w = e / s;
    }
#pragma unroll
    for (int j = 0; j < 4; ++j) {
      acc[j].x += w * xr[j].x;
      acc[j].y += w * xr[j].y;
      acc[j].z += w * xr[j].z;
      acc[j].w += w * xr[j].w;
    }
  }

  // reduce row-slot pairs (lane l <-> l^32) inside each wave
#pragma unroll
  for (int j = 0; j < 4; ++j) {
    acc[j].x += __shfl_xor(acc[j].x, 32);
    acc[j].y += __shfl_xor(acc[j].y, 32);
    acc[j].z += __shfl_xor(acc[j].z, 32);
    acc[j].w += __shfl_xor(acc[j].w, 32);
  }

  __shared__ float red[4][ROW_];  // 8 KiB: one 512-float partial per wave
  const int wave = tid >> 6;
  const int lane = tid & 63;
  if (lane < 32) {
    float4* dst = reinterpret_cast<float4*>(&red[wave][c2 * D2_]);
#pragma unroll
    for (int k = 0; k < 4; ++k) {
      const int jj = (k + c2) & 3;  // stagger to spread LDS banks
      dst[jj] = acc[jj];
    }
  }
  __syncthreads();
  if (tid < ROW_ / 4) {
    float4 s = make_float4(0.f, 0.f, 0.f, 0.f);
#pragma unroll
    for (int w2 = 0; w2 < 4; ++w2) {
      const float4 p = reinterpret_cast<const float4*>(red[w2])[tid];
      s.x += p.x; s.y += p.y; s.z += p.z; s.w += p.w;
    }
    reinterpret_cast<float4*>(P + ((size_t)b * BLOCKS_PER_B + blk) * ROW_)[tid] = s;
  }
}

// Fold the 32 per-block partials, apply scale + bias, squash over D2, write v.
__global__ __launch_bounds__(256) void squash_reduce(
    const float* __restrict__ P, const float* __restrict__ bias,
    float* __restrict__ out, float scale) {
  const int t = blockIdx.x * blockDim.x + threadIdx.x;  // one thread per (b,c2)
  if (t >= B_ * C2_) return;
  const int b  = t >> 5;
  const int c2 = t & 31;

  float4 s[4];
#pragma unroll
  for (int j = 0; j < 4; ++j) s[j] = make_float4(0.f, 0.f, 0.f, 0.f);
  const float* pb = P + (size_t)b * BLOCKS_PER_B * ROW_ + (size_t)c2 * D2_;
  for (int blk = 0; blk < BLOCKS_PER_B; ++blk) {
    const float4* p = reinterpret_cast<const float4*>(pb + (size_t)blk * ROW_);
#pragma unroll
    for (int j = 0; j < 4; ++j) {
      const float4 q = p[j];
      s[j].x += q.x; s[j].y += q.y; s[j].z += q.z; s[j].w += q.w;
    }
  }

  const float4* bp = reinterpret_cast<const float4*>(bias + (size_t)c2 * D2_);
  float ws[16];
  float sq = 0.f;
#pragma unroll
  for (int j = 0; j < 4; ++j) {
    const float4 bj = bp[j];
    ws[4 * j + 0] = s[j].x * scale + bj.x;
    ws[4 * j + 1] = s[j].y * scale + bj.y;
    ws[4 * j + 2] = s[j].z * scale + bj.z;
    ws[4 * j + 3] = s[j].w * scale + bj.w;
    sq += ws[4 * j + 0] * ws[4 * j + 0] + ws[4 * j + 1] * ws[4 * j + 1] +
          ws[4 * j + 2] * ws[4 * j + 2] + ws[4 * j + 3] * ws[4 * j + 3];
  }
  const float safe = sqrtf(sq + 1e-8f);
  const float f = sq / ((1.f + sq) * safe);

  float4* op = reinterpret_cast<float4*>(out + (size_t)b * ROW_ + (size_t)c2 * D2_);
#pragma unroll
  for (int j = 0; j < 4; ++j)
    op[j] = make_float4(f * ws[4 * j + 0], f * ws[4 * j + 1],
                        f * ws[4 * j + 2], f * ws[4 * j + 3]);
}

}  // namespace

extern "C" void kernel_launch(void* const* d_in, const int* in_sizes, int n_in,
                              void* d_out, int out_size, void* d_ws, size_t ws_size,
                              hipStream_t stream) {
  const float* x    = reinterpret_cast<const float*>(d_in[0]);  // digit_caps
  const float* bias = reinterpret_cast<const float*>(d_in[2]);
  float* out = reinterpret_cast<float*>(d_out);

  // workspace layout (floats): P[32*32*512]=2MiB, v0[16384], v1[16384]
  float* P  = reinterpret_cast<float*>(d_ws);
  float* v0 = P + (size_t)B_ * BLOCKS_PER_B * ROW_;
  float* v1 = v0 + (size_t)B_ * ROW_;

  const dim3 grid(B_ * BLOCKS_PER_B);
  const dim3 blk(256);

  routing_pass<0><<<grid, blk, 0, stream>>>(x, nullptr, nullptr, P);
  squash_reduce<<<4, 256, 0, stream>>>(P, bias, v0, 1.0f / C2_);
  routing_pass<1><<<grid, blk, 0, stream>>>(x, v0, nullptr, P);
  squash_reduce<<<4, 256, 0, stream>>>(P, bias, v1, 1.0f);
  routing_pass<2><<<grid, blk, 0, stream>>>(x, v0, v1, P);
  squash_reduce<<<4, 256, 0, stream>>>(P, bias, out, 1.0f);
}

// Round 2
// 173.558 us; speedup vs baseline: 1.0622x; 1.0622x over previous
//
#include <hip/hip_runtime.h>
#include <cstddef>

// DynamicRouting: B=32, C1=4096, C2=32, D2=16, 3 routing iterations.
// digit_caps_stopped == digit_caps (bit-identical) -> read d_in[0] only.
//
// iter0: w = 1/32 uniform            -> v0 = squash(colsum(x)/32 + bias)
// iter1: w1 = softmax_c2(x.v0)       -> v1 = squash(sum_c1 w1*x + bias)
// iter2: w2 = softmax_c2(x.(v0+v1))  -> out = squash(sum_c1 w2*x + bias)
//   (logit algebra: a0 + x.v1 = x.v0 + x.v1 = x.(v0+v1) -- one dot, not two)

namespace {
typedef float v2f __attribute__((ext_vector_type(2)));

constexpr int B_  = 32;
constexpr int C1_ = 4096;
constexpr int C2_ = 32;
constexpr int D2_ = 16;
constexpr int ROW_ = C2_ * D2_;      // 512 floats per (b,c1)
constexpr int BPB  = 64;             // partial blocks per batch element
constexpr int C1B  = C1_ / BPB;      // 64 rows per block

// v_pk_fma_f32: c = a*b + c (packed 2xf32, VOP3P) -- halves FMA instr count.
__device__ inline void pk_fma(v2f& c, v2f a, v2f b) {
  asm("v_pk_fma_f32 %0, %1, %2, %0" : "+v"(c) : "v"(a), "v"(b));
}
__device__ inline void pk_add(v2f& c, v2f a) {
  asm("v_pk_add_f32 %0, %1, %0" : "+v"(c) : "v"(a));
}

template <int PHASE>
__global__ __launch_bounds__(256) void routing_pass(
    const float* __restrict__ x, const float* __restrict__ v0,
    const float* __restrict__ v1, float* __restrict__ P /*[B][BPB][512]*/) {
  const int tid = threadIdx.x;
  const int c2  = tid & 31;   // lane's capsule2 index
  const int rs  = tid >> 5;   // row slot 0..7
  const int b   = blockIdx.x / BPB;
  const int blk = blockIdx.x % BPB;

  v2f va[8];  // logit vector: v0 (phase1) or v0+v1 (phase2)
  if (PHASE >= 1) {
    const v2f* vp = reinterpret_cast<const v2f*>(v0 + (size_t)b * ROW_ + c2 * D2_);
#pragma unroll
    for (int j = 0; j < 8; ++j) va[j] = vp[j];
    if (PHASE == 2) {
      const v2f* wp = reinterpret_cast<const v2f*>(v1 + (size_t)b * ROW_ + c2 * D2_);
#pragma unroll
      for (int j = 0; j < 8; ++j) { va[j].x += wp[j].x; va[j].y += wp[j].y; }
    }
  }

  v2f acc[8];
#pragma unroll
  for (int j = 0; j < 8; ++j) { acc[j].x = 0.f; acc[j].y = 0.f; }

  const size_t base =
      ((size_t)b * C1_ + (size_t)blk * C1B) * ROW_ + (size_t)c2 * D2_;
#pragma unroll 2
  for (int r = rs; r < C1B; r += 8) {
    float4 x4[4];
    const float4* xp = reinterpret_cast<const float4*>(x + base + (size_t)r * ROW_);
#pragma unroll
    for (int j = 0; j < 4; ++j) x4[j] = xp[j];
    v2f* x2 = reinterpret_cast<v2f*>(x4);

    if (PHASE == 0) {
#pragma unroll
      for (int j = 0; j < 8; ++j) pk_add(acc[j], x2[j]);
    } else {
      v2f dp; dp.x = 0.f; dp.y = 0.f;
#pragma unroll
      for (int j = 0; j < 8; ++j) pk_fma(dp, x2[j], va[j]);
      const float a = dp.x + dp.y;
      // softmax over the 32-lane c2 group; |a| <~ 15 so exp w/o max-shift is safe
      const float e = __expf(a);
      float s = e;
#pragma unroll
      for (int off = 16; off; off >>= 1) s += __shfl_xor(s, off, 32);
      const float w = e * __builtin_amdgcn_rcpf(s);
      v2f w2; w2.x = w; w2.y = w;
#pragma unroll
      for (int j = 0; j < 8; ++j) pk_fma(acc[j], x2[j], w2);
    }
  }

  // reduce row-slot pairs (lane l <-> l^32) inside each wave
  float* af = reinterpret_cast<float*>(acc);
#pragma unroll
  for (int k = 0; k < 16; ++k) af[k] += __shfl_xor(af[k], 32);

  __shared__ float red[4][ROW_];  // 8 KiB: one 512-float partial per wave
  const int wave = tid >> 6;
  const int lane = tid & 63;
  if (lane < 32) {
    float4* dst = reinterpret_cast<float4*>(&red[wave][c2 * D2_]);
    const float4* s4 = reinterpret_cast<const float4*>(acc);
#pragma unroll
    for (int k = 0; k < 4; ++k) {
      const int jj = (k + c2) & 3;  // stagger to spread LDS banks
      dst[jj] = s4[jj];
    }
  }
  __syncthreads();
  if (tid < ROW_ / 4) {
    float4 s = make_float4(0.f, 0.f, 0.f, 0.f);
#pragma unroll
    for (int w2i = 0; w2i < 4; ++w2i) {
      const float4 p = reinterpret_cast<const float4*>(red[w2i])[tid];
      s.x += p.x; s.y += p.y; s.z += p.z; s.w += p.w;
    }
    reinterpret_cast<float4*>(P + ((size_t)b * BPB + blk) * ROW_)[tid] = s;
  }
}

// Fold BPB per-block partials, apply scale + bias, squash over D2, write v.
// One thread per (b,c2,d2-quad): 4096 threads; squash norm via 4-lane shfl.
__global__ __launch_bounds__(256) void squash_reduce(
    const float* __restrict__ P, const float* __restrict__ bias,
    float* __restrict__ out, float scale) {
  const int gid = blockIdx.x * 256 + threadIdx.x;
  const int j  = gid & 3;
  const int c2 = (gid >> 2) & 31;
  const int b  = gid >> 7;
  if (b >= B_) return;

  const float* pb = P + (size_t)b * BPB * ROW_ + c2 * D2_ + j * 4;
  float4 s = make_float4(0.f, 0.f, 0.f, 0.f);
#pragma unroll 8
  for (int k = 0; k < BPB; ++k) {
    const float4 q = *reinterpret_cast<const float4*>(pb + (size_t)k * ROW_);
    s.x += q.x; s.y += q.y; s.z += q.z; s.w += q.w;
  }

  const float4 bj = *reinterpret_cast<const float4*>(bias + c2 * D2_ + j * 4);
  float4 t;
  t.x = s.x * scale + bj.x;
  t.y = s.y * scale + bj.y;
  t.z = s.z * scale + bj.z;
  t.w = s.w * scale + bj.w;

  float sq = t.x * t.x + t.y * t.y + t.z * t.z + t.w * t.w;
  sq += __shfl_xor(sq, 1, 4);
  sq += __shfl_xor(sq, 2, 4);
  const float safe = sqrtf(sq + 1e-8f);
  const float f = sq / ((1.f + sq) * safe);

  float4 o;
  o.x = f * t.x; o.y = f * t.y; o.z = f * t.z; o.w = f * t.w;
  *reinterpret_cast<float4*>(out + (size_t)b * ROW_ + c2 * D2_ + j * 4) = o;
}

}  // namespace

extern "C" void kernel_launch(void* const* d_in, const int* in_sizes, int n_in,
                              void* d_out, int out_size, void* d_ws, size_t ws_size,
                              hipStream_t stream) {
  const float* x    = reinterpret_cast<const float*>(d_in[0]);  // digit_caps
  const float* bias = reinterpret_cast<const float*>(d_in[2]);
  float* out = reinterpret_cast<float*>(d_out);

  // workspace (floats): P[32*64*512]=4MiB, v0[16384], v1[16384]
  float* P  = reinterpret_cast<float*>(d_ws);
  float* v0 = P + (size_t)B_ * BPB * ROW_;
  float* v1 = v0 + (size_t)B_ * ROW_;

  const dim3 grid(B_ * BPB);
  const dim3 blk(256);
  const dim3 sgrid((B_ * C2_ * 4 + 255) / 256);

  routing_pass<0><<<grid, blk, 0, stream>>>(x, nullptr, nullptr, P);
  squash_reduce<<<sgrid, blk, 0, stream>>>(P, bias, v0, 1.0f / C2_);
  routing_pass<1><<<grid, blk, 0, stream>>>(x, v0, nullptr, P);
  squash_reduce<<<sgrid, blk, 0, stream>>>(P, bias, v1, 1.0f);
  routing_pass<2><<<grid, blk, 0, stream>>>(x, v0, v1, P);
  squash_reduce<<<sgrid, blk, 0, stream>>>(P, bias, out, 1.0f);
}